// Round 2
// baseline (159.462 us; speedup 1.0000x reference)
//
#include <hip/hip_runtime.h>
#include <hip/hip_bf16.h>

typedef unsigned short u16;
typedef unsigned int u32;
typedef float f32x4 __attribute__((ext_vector_type(4)));
typedef short bf16x8 __attribute__((ext_vector_type(8)));   // 8 bf16 as i16 (4 VGPRs)

#define LOG2E 1.4426950408889634f

static __device__ __forceinline__ u16 f2bf(float f){
  __hip_bfloat16 h = __float2bfloat16(f);
  return __builtin_bit_cast(u16, h);
}
static __device__ __forceinline__ float bf2f(u16 u){
  __hip_bfloat16 h = __builtin_bit_cast(__hip_bfloat16, u);
  return __bfloat162float(h);
}
static __device__ __forceinline__ float fexp2(float x){
#if __has_builtin(__builtin_amdgcn_exp2f)
  return __builtin_amdgcn_exp2f(x);
#else
  return exp2f(x);
#endif
}
static __device__ __forceinline__ u32 pack2(float a, float b){
  return (u32)f2bf(a) | ((u32)f2bf(b) << 16);
}
static __device__ __forceinline__ f32x4 mf(bf16x8 a, bf16x8 b, f32x4 c){
  return __builtin_amdgcn_mfma_f32_16x16x32_bf16(a, b, c, 0, 0, 0);
}

// ---------------------------------------------------------------------------
// Kernel 1: QKV projection. grid (64, 4) x 256 threads.
// Block covers n-range of 64 for one batch. Wave w covers n-sub [w*16, w*16+16),
// lane = cg*16 + nl: nl -> n, cg -> 64-channel slice. 48 accumulators/lane,
// shfl_xor reduce over cg, then role-split pack: cg0 -> q hi/lo, cg1 -> k
// (kcat=[kh|kl], khz=[kh|0]), cg2 -> vT.
// ---------------------------------------------------------------------------
__global__ __launch_bounds__(256, 2) void qkv_kernel(
    const float* __restrict__ x,
    const float* __restrict__ Wq, const float* __restrict__ bq,
    const float* __restrict__ Wk, const float* __restrict__ bk,
    const float* __restrict__ Wv, const float* __restrict__ bv,
    u16* __restrict__ qh, u16* __restrict__ ql,
    u16* __restrict__ kcat, u16* __restrict__ khz, u16* __restrict__ vT)
{
  __shared__ float wlds[48*256];   // [o=48][c=256], float4-swizzled over cg
  int t = threadIdx.x;
  int nt = blockIdx.x, b = blockIdx.y;
  for (int idx = t; idx < 48*256; idx += 256) {
    int o = idx >> 8, c = idx & 255;
    int m = o >> 4, d = o & 15;
    const float* W = (m==0) ? Wq : (m==1) ? Wk : Wv;
    int cg = c >> 6, cc4 = (c >> 2) & 15, j = c & 3;
    int pos = (o << 8) + (cg << 6) + (((cc4 ^ cg) & 15) << 2) + j;
    wlds[pos] = W[d*256 + c];
  }
  __syncthreads();
  int w = t >> 6, lane = t & 63;
  int nl = lane & 15, cg = lane >> 4;
  int n = nt*64 + w*16 + nl;
  float acc[48];
  #pragma unroll
  for (int o = 0; o < 48; ++o) acc[o] = 0.f;
  const float* xb = x + (b << 20) + n;
  const float4* wl4 = (const float4*)wlds;
  #pragma unroll 2
  for (int cc4 = 0; cc4 < 16; ++cc4) {
    int c0 = cg*64 + cc4*4;
    float x0 = xb[(c0+0) << 12];
    float x1 = xb[(c0+1) << 12];
    float x2 = xb[(c0+2) << 12];
    float x3 = xb[(c0+3) << 12];
    int f4b = (cg << 4) + (cc4 ^ cg);
    #pragma unroll
    for (int o = 0; o < 48; ++o) {
      float4 wv = wl4[(o << 6) + f4b];
      acc[o] += wv.x*x0 + wv.y*x1 + wv.z*x2 + wv.w*x3;
    }
  }
  #pragma unroll
  for (int o = 0; o < 48; ++o) {
    acc[o] += __shfl_xor(acc[o], 16, 64);
    acc[o] += __shfl_xor(acc[o], 32, 64);
  }
  if (cg == 0) {
    alignas(16) u16 hq[16]; alignas(16) u16 lq[16];
    #pragma unroll
    for (int d = 0; d < 16; ++d) {
      float v_ = acc[d] + bq[d];
      u16 h = f2bf(v_);
      hq[d] = h;
      lq[d] = f2bf(v_ - bf2f(h));
    }
    int4* dst = (int4*)(qh + ((size_t)((b << 12) + n))*16);
    dst[0] = ((int4*)hq)[0]; dst[1] = ((int4*)hq)[1];
    int4* dst2 = (int4*)(ql + ((size_t)((b << 12) + n))*16);
    dst2[0] = ((int4*)lq)[0]; dst2[1] = ((int4*)lq)[1];
  } else if (cg == 1) {
    alignas(16) u16 kk[32]; alignas(16) u16 kz2[32];
    #pragma unroll
    for (int d = 0; d < 16; ++d) {
      float v_ = acc[16+d] + bk[d];
      u16 h = f2bf(v_);
      u16 l_ = f2bf(v_ - bf2f(h));
      kk[d] = h; kk[16+d] = l_;
      kz2[d] = h; kz2[16+d] = 0;
    }
    int4* dst = (int4*)(kcat + ((size_t)((b << 12) + n))*32);
    #pragma unroll
    for (int q_ = 0; q_ < 4; ++q_) dst[q_] = ((int4*)kk)[q_];
    int4* dst2 = (int4*)(khz + ((size_t)((b << 12) + n))*32);
    #pragma unroll
    for (int q_ = 0; q_ < 4; ++q_) dst2[q_] = ((int4*)kz2)[q_];
  } else if (cg == 2) {
    #pragma unroll
    for (int d = 0; d < 16; ++d) {
      float v_ = acc[32+d] + bv[d];
      vT[((size_t)((b*16 + d) << 12)) + n] = f2bf(v_);
    }
  }
}

// ---------------------------------------------------------------------------
// Kernel 2: flash attention (no-max softmax, split-K=2).
// grid (64, 4, 2) x 256 threads. Wave owns 16 queries; per 64-key chunk:
// scores^T = kcat.[qh|qh] + khz.[ql|ql]  (fp32-accurate via Dekker split),
// p = exp2(s*log2e), p -> swizzled per-wave LDS tile -> PV B-frag;
// av accumulated as MFMA C. No max-tracking: scores bounded ~|q||k| < 80,
// exp stays finite in fp32/bf16.
// ---------------------------------------------------------------------------
struct Frags { bf16x8 ac0,ac1,ac2,ac3, az0,az1,az2,az3, v0,v1; };

static __device__ __forceinline__ Frags loadFrags(
  const u16* __restrict__ kc, const u16* __restrict__ kz,
  const u16* __restrict__ vp, int kb, int i, int g)
{
  Frags f;
  const u16* a0 = kc + (kb + i)*32 + g*8;
  f.ac0 = *(const bf16x8*)(a0);
  f.ac1 = *(const bf16x8*)(a0 + 512);
  f.ac2 = *(const bf16x8*)(a0 + 1024);
  f.ac3 = *(const bf16x8*)(a0 + 1536);
  const u16* z0 = kz + (kb + i)*32 + g*8;
  f.az0 = *(const bf16x8*)(z0);
  f.az1 = *(const bf16x8*)(z0 + 512);
  f.az2 = *(const bf16x8*)(z0 + 1024);
  f.az3 = *(const bf16x8*)(z0 + 1536);
  const u16* v0p = vp + kb + g*8;
  f.v0 = *(const bf16x8*)(v0p);
  f.v1 = *(const bf16x8*)(v0p + 32);
  return f;
}

__global__ __launch_bounds__(256, 2) void attn_kernel(
    const u16* __restrict__ qh, const u16* __restrict__ ql,
    const u16* __restrict__ kcat, const u16* __restrict__ khz,
    const u16* __restrict__ vT,
    float* __restrict__ av_part, float* __restrict__ l_part)
{
  __shared__ char plds[4*2048];    // per-wave 16x64 bf16 P^T tile, XOR-swizzled
  int tid = threadIdx.x, wid = tid >> 6, lane = tid & 63;
  int g = lane >> 4, i = lane & 15;
  int b = blockIdx.y, s = blockIdx.z;
  int qidx = blockIdx.x*64 + wid*16 + i;
  char* myp = plds + wid*2048;
  int rowb = i*128;
  int mi = (i & 7) << 4;

  bf16x8 Bqh = *(const bf16x8*)(qh + ((size_t)((b << 12) + qidx))*16 + ((g & 1) << 3));
  bf16x8 Bql = *(const bf16x8*)(ql + ((size_t)((b << 12) + qidx))*16 + ((g & 1) << 3));
  const u16* kc = kcat + (size_t)b*4096*32;
  const u16* kz = khz  + (size_t)b*4096*32;
  const u16* vp = vT   + ((size_t)(b*16 + i) << 12);

  f32x4 av = {0.f,0.f,0.f,0.f};
  float lsum = 0.f;
  int kb0 = s*2048;
  Frags cu = loadFrags(kc, kz, vp, kb0, i, g);
  #pragma unroll 2
  for (int it = 0; it < 32; ++it) {
    int kb = kb0 + it*64;
    int kbn = (it < 31) ? (kb + 64) : kb;
    Frags nx = loadFrags(kc, kz, vp, kbn, i, g);
    f32x4 z4 = {0.f,0.f,0.f,0.f};
    f32x4 s0 = mf(cu.ac0, Bqh, z4); s0 = mf(cu.az0, Bql, s0);
    f32x4 s1 = mf(cu.ac1, Bqh, z4); s1 = mf(cu.az1, Bql, s1);
    f32x4 s2 = mf(cu.ac2, Bqh, z4); s2 = mf(cu.az2, Bql, s2);
    f32x4 s3 = mf(cu.ac3, Bqh, z4); s3 = mf(cu.az3, Bql, s3);
    f32x4 p0, p1, p2, p3;
    #pragma unroll
    for (int r = 0; r < 4; ++r) {
      p0[r] = fexp2(s0[r]*LOG2E);
      p1[r] = fexp2(s1[r]*LOG2E);
      p2[r] = fexp2(s2[r]*LOG2E);
      p3[r] = fexp2(s3[r]*LOG2E);
    }
    lsum += (p0[0]+p0[1]+p0[2]+p0[3]) + (p1[0]+p1[1]+p1[2]+p1[3])
          + (p2[0]+p2[1]+p2[2]+p2[3]) + (p3[0]+p3[1]+p3[2]+p3[3]);
    // P^T tile: row = query i (128B), byte 2*keylocal, XOR-swizzled by mi.
    // (8g+c)^mi stays 8-aligned (mi is a 16-multiple) -> b64 pair stores.
    *(uint2*)(myp + rowb + (((8*g)      ) ^ mi)) =
        (uint2){ pack2(p0[0], p0[1]), pack2(p0[2], p0[3]) };
    *(uint2*)(myp + rowb + (((8*g) + 32 ) ^ mi)) =
        (uint2){ pack2(p1[0], p1[1]), pack2(p1[2], p1[3]) };
    *(uint2*)(myp + rowb + (((8*g) + 64 ) ^ mi)) =
        (uint2){ pack2(p2[0], p2[1]), pack2(p2[2], p2[3]) };
    *(uint2*)(myp + rowb + (((8*g) + 96 ) ^ mi)) =
        (uint2){ pack2(p3[0], p3[1]), pack2(p3[2], p3[3]) };
    bf16x8 Bp0 = *(const bf16x8*)(myp + rowb + (( 0 + 16*g) ^ mi));
    bf16x8 Bp1 = *(const bf16x8*)(myp + rowb + ((64 + 16*g) ^ mi));
    av = mf(cu.v0, Bp0, av);
    av = mf(cu.v1, Bp1, av);
    cu = nx;
  }
  float lt = lsum;
  lt += __shfl_xor(lt, 16, 64);
  lt += __shfl_xor(lt, 32, 64);
  float* avp = av_part + ((size_t)((s*4 + b)*16) << 12);
  #pragma unroll
  for (int r = 0; r < 4; ++r)
    avp[((size_t)(4*g + r) << 12) + qidx] = av[r];
  if (lane < 16)
    l_part[((size_t)((s*4 + b)) << 12) + qidx] = lt;
}

// ---------------------------------------------------------------------------
// Kernel 3: merge key-splits + output projection. grid (16,16,4) x 256.
// ---------------------------------------------------------------------------
__global__ __launch_bounds__(256, 4) void outproj_kernel(
    const float* __restrict__ av_part, const float* __restrict__ l_part,
    const float* __restrict__ Wo, const float* __restrict__ bo,
    float* __restrict__ out)
{
  __shared__ float wl[16][16];
  __shared__ float bol[16];
  int t = threadIdx.x;
  int ct = blockIdx.x, ntile = blockIdx.y, b = blockIdx.z;
  wl[t >> 4][t & 15] = Wo[(ct*16 + (t >> 4))*16 + (t & 15)];
  if (t < 16) bol[t] = bo[ct*16 + t];
  __syncthreads();
  int n = ntile*256 + t;
  float l0 = l_part[((size_t)b << 12) + n];
  float l1 = l_part[((size_t)(4 + b) << 12) + n];
  float inv = 1.f / (l0 + l1);
  float avv[16];
  #pragma unroll
  for (int d = 0; d < 16; ++d) {
    float a0 = av_part[((size_t)(b*16 + d) << 12) + n];
    float a1 = av_part[((size_t)((4 + b)*16 + d) << 12) + n];
    avv[d] = (a0 + a1) * inv;
  }
  #pragma unroll
  for (int cc = 0; cc < 16; ++cc) {
    float o = bol[cc];
    #pragma unroll
    for (int d = 0; d < 16; ++d) o += wl[cc][d] * avv[d];
    out[((size_t)(b*256 + ct*16 + cc) << 12) + n] = o;
  }
}

extern "C" void kernel_launch(void* const* d_in, const int* in_sizes, int n_in,
                              void* d_out, int out_size, void* d_ws, size_t ws_size,
                              hipStream_t stream) {
  (void)in_sizes; (void)n_in; (void)out_size; (void)ws_size;
  const float* x  = (const float*)d_in[0];
  const float* Wq = (const float*)d_in[1];
  const float* bq = (const float*)d_in[2];
  const float* Wk = (const float*)d_in[3];
  const float* bk = (const float*)d_in[4];
  const float* Wv = (const float*)d_in[5];
  const float* bv = (const float*)d_in[6];
  const float* Wo = (const float*)d_in[7];
  const float* bo = (const float*)d_in[8];
  float* out = (float*)d_out;
  char* ws = (char*)d_ws;

  u16* qh   = (u16*)(ws + 0);        //  512 KB  [B][N][16]
  u16* ql   = (u16*)(ws + 524288);   //  512 KB  [B][N][16]
  u16* kcat = (u16*)(ws + 1048576);  // 1024 KB  [B][N][32] = [kh|kl]
  u16* khz  = (u16*)(ws + 2097152);  // 1024 KB  [B][N][32] = [kh|0]
  u16* vT   = (u16*)(ws + 3145728);  //  512 KB  [B][16][N]
  float* av_part = (float*)(ws + 3670016); // 2 MB  [2][B][16][N]
  float* l_part  = (float*)(ws + 5767168); // 128 KB [2][B][N]

  qkv_kernel<<<dim3(64, 4), dim3(256), 0, stream>>>(
      x, Wq, bq, Wk, bk, Wv, bv, qh, ql, kcat, khz, vT);
  attn_kernel<<<dim3(64, 4, 2), dim3(256), 0, stream>>>(
      qh, ql, kcat, khz, vT, av_part, l_part);
  outproj_kernel<<<dim3(16, 16, 4), dim3(256), 0, stream>>>(
      av_part, l_part, Wo, bo, out);
}

// Round 5
// 151.794 us; speedup vs baseline: 1.0505x; 1.0505x over previous
//
#include <hip/hip_runtime.h>
#include <hip/hip_bf16.h>

typedef unsigned short u16;
typedef unsigned int u32;
typedef float f32x4 __attribute__((ext_vector_type(4)));
typedef short bf16x8 __attribute__((ext_vector_type(8)));   // 8 bf16 as i16 (4 VGPRs)

#define LOG2E 1.4426950408889634f

static __device__ __forceinline__ u16 f2bf(float f){
  __hip_bfloat16 h = __float2bfloat16(f);
  return __builtin_bit_cast(u16, h);
}
static __device__ __forceinline__ float bf2f(u16 u){
  __hip_bfloat16 h = __builtin_bit_cast(__hip_bfloat16, u);
  return __bfloat162float(h);
}
static __device__ __forceinline__ float fexp2(float x){
#if __has_builtin(__builtin_amdgcn_exp2f)
  return __builtin_amdgcn_exp2f(x);
#else
  return exp2f(x);
#endif
}
static __device__ __forceinline__ u32 pack2(float a, float b){
  return (u32)f2bf(a) | ((u32)f2bf(b) << 16);
}
static __device__ __forceinline__ f32x4 mf(bf16x8 a, bf16x8 b, f32x4 c){
  return __builtin_amdgcn_mfma_f32_16x16x32_bf16(a, b, c, 0, 0, 0);
}

// ---------------------------------------------------------------------------
// Kernel 1: QKV projection. grid (64, 4, 3) x 256 threads (m = q/k/v split).
// Block computes matrix m for 64 n. Wave w covers n-sub [w*16,+16); lane =
// cg*16+nl: nl->n, cg->64-channel slice. 16 acc/lane, butterfly over cg gives
// ALL lanes the full sums -> fully coalesced role-split stores.
// ---------------------------------------------------------------------------
__global__ __launch_bounds__(256, 2) void qkv_kernel(
    const float* __restrict__ x,
    const float* __restrict__ Wq, const float* __restrict__ bq,
    const float* __restrict__ Wk, const float* __restrict__ bk,
    const float* __restrict__ Wv, const float* __restrict__ bv,
    u16* __restrict__ qh, u16* __restrict__ ql,
    u16* __restrict__ kcat, u16* __restrict__ vT)
{
  __shared__ float wlds[16*256];   // [d=16][c=256], float4-swizzled over cg
  int t = threadIdx.x;
  int nt = blockIdx.x, b = blockIdx.y, m = blockIdx.z;
  const float* W    = (m==0) ? Wq : (m==1) ? Wk : Wv;
  const float* bias = (m==0) ? bq : (m==1) ? bk : bv;
  for (int idx = t; idx < 16*256; idx += 256) {
    int d = idx >> 8, c = idx & 255;
    int cg = c >> 6, cc4 = (c >> 2) & 15, j = c & 3;
    int pos = (d << 8) + (cg << 6) + ((cc4 ^ cg) << 2) + j;
    wlds[pos] = W[d*256 + c];
  }
  __syncthreads();
  int w = t >> 6, lane = t & 63;
  int nl = lane & 15, cg = lane >> 4;
  int n = nt*64 + w*16 + nl;
  float acc[16];
  #pragma unroll
  for (int d = 0; d < 16; ++d) acc[d] = 0.f;
  const float* xb = x + (b << 20) + n;
  const float4* wl4 = (const float4*)wlds;
  #pragma unroll 4
  for (int cc4 = 0; cc4 < 16; ++cc4) {
    int c0 = cg*64 + cc4*4;
    float x0 = xb[(c0+0) << 12];
    float x1 = xb[(c0+1) << 12];
    float x2 = xb[(c0+2) << 12];
    float x3 = xb[(c0+3) << 12];
    int f4b = (cg << 4) + (cc4 ^ cg);
    #pragma unroll
    for (int d = 0; d < 16; ++d) {
      float4 wv = wl4[(d << 6) + f4b];
      acc[d] += wv.x*x0 + wv.y*x1 + wv.z*x2 + wv.w*x3;
    }
  }
  #pragma unroll
  for (int d = 0; d < 16; ++d) {
    acc[d] += __shfl_xor(acc[d], 16, 64);
    acc[d] += __shfl_xor(acc[d], 32, 64);    // all 64 lanes: full sums
  }
  if (m == 2) {
    // vT[b*16+d][n], 4 d-planes per lane
    #pragma unroll
    for (int jj = 0; jj < 4; ++jj) {
      int d = cg*4 + jj;
      vT[((size_t)((b*16 + d)) << 12) + n] = f2bf(acc[d] + bias[d]);
    }
  } else {
    int d0 = (cg & 1) * 8, lo = cg >> 1;
    alignas(16) u16 vals[8];
    #pragma unroll
    for (int jj = 0; jj < 8; ++jj) {
      int d = d0 + jj;
      float v_ = acc[d] + bias[d];
      u16 h = f2bf(v_);
      vals[jj] = lo ? f2bf(v_ - bf2f(h)) : h;
    }
    u16* dst;
    if (m == 0) {
      // q: qh/ql rows of 16 u16; cg0->qh lo-half, cg1->qh hi, cg2/3->ql
      u16* base = lo ? ql : qh;
      dst = base + (((size_t)(b << 12) + n) << 4) + d0;
    } else {
      // k: kcat rows [kh(16)|kl(16)]; quarter cg at offset cg*8
      dst = kcat + (((size_t)(b << 12) + n) << 5) + cg*8;
    }
    *(int4*)dst = *(const int4*)vals;
  }
}

// ---------------------------------------------------------------------------
// Kernel 2: flash attention (no-max softmax, split-K = gridDim.z).
// grid (64, 4, nsplit) x 256 threads. Wave owns 16 queries; per 64-key chunk:
// scores^T = kcat.[qh|qh] + kcat.[ql_masked|0]  (fp32-accurate Dekker split;
// the B-side mask (g<2?Bql:0) is loop-invariant), p = exp2(s*log2e),
// p -> swizzled per-wave LDS tile -> PV B-frag; av accumulated as MFMA C.
// ---------------------------------------------------------------------------
struct Frags { bf16x8 ac0,ac1,ac2,ac3, v0,v1; };

static __device__ __forceinline__ Frags loadFrags(
  const u16* __restrict__ kc, const u16* __restrict__ vp,
  int kb, int i, int g)
{
  Frags f;
  const u16* a0 = kc + (kb + i)*32 + g*8;
  f.ac0 = *(const bf16x8*)(a0);
  f.ac1 = *(const bf16x8*)(a0 + 512);
  f.ac2 = *(const bf16x8*)(a0 + 1024);
  f.ac3 = *(const bf16x8*)(a0 + 1536);
  const u16* v0p = vp + kb + g*8;
  f.v0 = *(const bf16x8*)(v0p);
  f.v1 = *(const bf16x8*)(v0p + 32);
  return f;
}

__global__ __launch_bounds__(256, 2) void attn_kernel(
    const u16* __restrict__ qh, const u16* __restrict__ ql,
    const u16* __restrict__ kcat, const u16* __restrict__ vT,
    float* __restrict__ av_part, float* __restrict__ l_part)
{
  __shared__ char plds[4*2048];    // per-wave 16x64 bf16 P^T tile, XOR-swizzled
  int tid = threadIdx.x, wid = tid >> 6, lane = tid & 63;
  int g = lane >> 4, i = lane & 15;
  int b = blockIdx.y, s = blockIdx.z;
  int nsplit = gridDim.z;
  int iters = 64 / nsplit;
  int qidx = blockIdx.x*64 + wid*16 + i;
  char* myp = plds + wid*2048;
  int rowb = i*128;
  int mi = (i & 7) << 4;

  bf16x8 Bqh = *(const bf16x8*)(qh + ((size_t)((b << 12) + qidx))*16 + ((g & 1) << 3));
  bf16x8 Bql = *(const bf16x8*)(ql + ((size_t)((b << 12) + qidx))*16 + ((g & 1) << 3));
  if (g >= 2) {   // loop-invariant B-side mask: [ql|0] over the k=32 dim
    #pragma unroll
    for (int e = 0; e < 8; ++e) Bql[e] = 0;
  }
  const u16* kc = kcat + (size_t)b*4096*32;
  const u16* vp = vT   + ((size_t)(b*16 + i) << 12);

  f32x4 av = {0.f,0.f,0.f,0.f};
  float lsum = 0.f;
  int kb0 = s*(iters*64);
  Frags cu = loadFrags(kc, vp, kb0, i, g);
  #pragma unroll 2
  for (int it = 0; it < iters; ++it) {
    int kb = kb0 + it*64;
    int kbn = (it+1 < iters) ? (kb + 64) : kb;
    Frags nx = loadFrags(kc, vp, kbn, i, g);
    f32x4 z4 = {0.f,0.f,0.f,0.f};
    f32x4 s0 = mf(cu.ac0, Bqh, z4); s0 = mf(cu.ac0, Bql, s0);
    f32x4 s1 = mf(cu.ac1, Bqh, z4); s1 = mf(cu.ac1, Bql, s1);
    f32x4 s2 = mf(cu.ac2, Bqh, z4); s2 = mf(cu.ac2, Bql, s2);
    f32x4 s3 = mf(cu.ac3, Bqh, z4); s3 = mf(cu.ac3, Bql, s3);
    f32x4 p0, p1, p2, p3;
    #pragma unroll
    for (int r = 0; r < 4; ++r) {
      p0[r] = fexp2(s0[r]*LOG2E);
      p1[r] = fexp2(s1[r]*LOG2E);
      p2[r] = fexp2(s2[r]*LOG2E);
      p3[r] = fexp2(s3[r]*LOG2E);
    }
    lsum += (p0[0]+p0[1]+p0[2]+p0[3]) + (p1[0]+p1[1]+p1[2]+p1[3])
          + (p2[0]+p2[1]+p2[2]+p2[3]) + (p3[0]+p3[1]+p3[2]+p3[3]);
    // P^T tile: row = query i (128B), byte 2*keylocal, XOR-swizzled by mi.
    *(uint2*)(myp + rowb + (((8*g)      ) ^ mi)) =
        (uint2){ pack2(p0[0], p0[1]), pack2(p0[2], p0[3]) };
    *(uint2*)(myp + rowb + (((8*g) + 32 ) ^ mi)) =
        (uint2){ pack2(p1[0], p1[1]), pack2(p1[2], p1[3]) };
    *(uint2*)(myp + rowb + (((8*g) + 64 ) ^ mi)) =
        (uint2){ pack2(p2[0], p2[1]), pack2(p2[2], p2[3]) };
    *(uint2*)(myp + rowb + (((8*g) + 96 ) ^ mi)) =
        (uint2){ pack2(p3[0], p3[1]), pack2(p3[2], p3[3]) };
    bf16x8 Bp0 = *(const bf16x8*)(myp + rowb + (( 0 + 16*g) ^ mi));
    bf16x8 Bp1 = *(const bf16x8*)(myp + rowb + ((64 + 16*g) ^ mi));
    av = mf(cu.v0, Bp0, av);
    av = mf(cu.v1, Bp1, av);
    cu = nx;
  }
  float lt = lsum;
  lt += __shfl_xor(lt, 16, 64);
  lt += __shfl_xor(lt, 32, 64);
  float* avp = av_part + ((size_t)((s*4 + b)*16) << 12);
  #pragma unroll
  for (int r = 0; r < 4; ++r)
    avp[((size_t)(4*g + r) << 12) + qidx] = av[r];
  if (lane < 16)
    l_part[((size_t)((s*4 + b)) << 12) + qidx] = lt;
}

// ---------------------------------------------------------------------------
// Kernel 3: merge key-splits + output projection. grid (16,16,4) x 256.
// ---------------------------------------------------------------------------
__global__ __launch_bounds__(256, 4) void outproj_kernel(
    const float* __restrict__ av_part, const float* __restrict__ l_part,
    const float* __restrict__ Wo, const float* __restrict__ bo,
    float* __restrict__ out, int nsplit)
{
  __shared__ float wl[16][16];
  __shared__ float bol[16];
  int t = threadIdx.x;
  int ct = blockIdx.x, ntile = blockIdx.y, b = blockIdx.z;
  wl[t >> 4][t & 15] = Wo[(ct*16 + (t >> 4))*16 + (t & 15)];
  if (t < 16) bol[t] = bo[ct*16 + t];
  __syncthreads();
  int n = ntile*256 + t;
  float lsum = 0.f;
  for (int s = 0; s < nsplit; ++s)
    lsum += l_part[((size_t)(s*4 + b) << 12) + n];
  float inv = 1.f / lsum;
  float avv[16];
  #pragma unroll
  for (int d = 0; d < 16; ++d) avv[d] = 0.f;
  for (int s = 0; s < nsplit; ++s) {
    #pragma unroll
    for (int d = 0; d < 16; ++d)
      avv[d] += av_part[((size_t)((s*4 + b)*16 + d) << 12) + n];
  }
  #pragma unroll
  for (int d = 0; d < 16; ++d) avv[d] *= inv;
  #pragma unroll
  for (int cc = 0; cc < 16; ++cc) {
    float o = bol[cc];
    #pragma unroll
    for (int d = 0; d < 16; ++d) o += wl[cc][d] * avv[d];
    out[((size_t)(b*256 + ct*16 + cc) << 12) + n] = o;
  }
}

extern "C" void kernel_launch(void* const* d_in, const int* in_sizes, int n_in,
                              void* d_out, int out_size, void* d_ws, size_t ws_size,
                              hipStream_t stream) {
  (void)in_sizes; (void)n_in; (void)out_size;
  const float* x  = (const float*)d_in[0];
  const float* Wq = (const float*)d_in[1];
  const float* bq = (const float*)d_in[2];
  const float* Wk = (const float*)d_in[3];
  const float* bk = (const float*)d_in[4];
  const float* Wv = (const float*)d_in[5];
  const float* bv = (const float*)d_in[6];
  const float* Wo = (const float*)d_in[7];
  const float* bo = (const float*)d_in[8];
  float* out = (float*)d_out;
  char* ws = (char*)d_ws;

  // Fixed buffers: qh 512K, ql 512K, kcat 1M, vT 512K = 2.5 MB
  const size_t fixed = 2621440;
  const size_t per_split = 1048576 + 65536;   // av (1MB) + l (64KB) per split
  int nsplit = 8;
  while (nsplit > 1 && fixed + (size_t)nsplit*per_split > ws_size) nsplit >>= 1;

  u16* qh   = (u16*)(ws + 0);
  u16* ql   = (u16*)(ws + 524288);
  u16* kcat = (u16*)(ws + 1048576);
  u16* vT   = (u16*)(ws + 2097152);
  float* av_part = (float*)(ws + fixed);
  float* l_part  = (float*)(ws + fixed + (size_t)nsplit*1048576);

  qkv_kernel<<<dim3(64, 4, 3), dim3(256), 0, stream>>>(
      x, Wq, bq, Wk, bk, Wv, bv, qh, ql, kcat, vT);
  attn_kernel<<<dim3(64, 4, nsplit), dim3(256), 0, stream>>>(
      qh, ql, kcat, vT, av_part, l_part);
  outproj_kernel<<<dim3(16, 16, 4), dim3(256), 0, stream>>>(
      av_part, l_part, Wo, bo, out, nsplit);
}